// Round 3
// baseline (76.039 us; speedup 1.0000x reference)
//
#include <hip/hip_runtime.h>
#include <math.h>

#define B_MOL 64
#define A_MAX 48
#define NSPEC 4
#define NRS2 24
#define NRS3 20
#define NPAIRS 10
#define REP2 (NSPEC * NRS2)        // 96
#define REP3 (NPAIRS * NRS3 * 2)   // 400
#define REPTOT (REP2 + REP3)       // 496
#define TRIP_CAP 1084              // >= 47*46/2 = 1081

#define RCUT_F 6.0f
#define ETA2_F 0.32f
#define ETA3_F 2.7f
#define PI_F 3.14159265358979323846f
#define W3_F 12.4225780586f        // sqrt(2.7/pi)*13.4
#define SQRT_2PI_F 2.5066282746310002f

// closed-form triplet decode: t -> (a, c), a < c < m, row-major over a
__device__ __forceinline__ void decode_tri(int t, int m, int& a_out, int& c_out) {
    const float fm = (float)(2 * m - 1);
    const float disc = fm * fm - 8.0f * (float)t;   // <= 8649, integer-exact in f32
    const float sq = __builtin_amdgcn_sqrtf(disc);
    int a = (int)((fm - sq) * 0.5f);
    if (a < 0) a = 0;
    // fixup (executes <=1 iteration; guards sqrt rounding at row boundaries)
    while (a > 0 && (a * (2 * m - 1 - a)) / 2 > t) --a;
    while (((a + 1) * (2 * m - 1 - (a + 1))) / 2 <= t) ++a;
    a_out = a;
    c_out = t - (a * (2 * m - 1 - a)) / 2 + a + 1;
}

__global__ __launch_bounds__(256) void fchl_kernel(
    const float* __restrict__ X, const int* __restrict__ Z,
    const int* __restrict__ atom_counts, float* __restrict__ out)
{
    const int bi = blockIdx.x;           // b*A_MAX + i
    const int b = bi / A_MAX;
    const int i = bi % A_MAX;
    const int tid = threadIdx.x;

    __shared__ float sx[A_MAX], sy[A_MAX], sz[A_MAX];
    __shared__ int   sZa[A_MAX];
    // compacted neighbor list (ballot compaction preserves order => a<c <=> j<k)
    __shared__ float nb_dx[A_MAX], nb_dy[A_MAX], nb_dz[A_MAX];
    __shared__ float nb_r[A_MAX], nb_r2[A_MAX], nb_rinv[A_MAX];
    __shared__ float nb_fc[A_MAX], nb_mu[A_MAX], nb_i2s2[A_MAX], nb_pref[A_MAX];
    __shared__ int   nb_z[A_MAX];
    __shared__ int   nb_m;
    __shared__ int   bcnt[NPAIRS], bstart[NPAIRS];
    __shared__ unsigned short pq[TRIP_CAP];          // p | (rank<<4)
    __shared__ float4 trip[TRIP_CAP];                // (wc, ws, d, 0), bucket-sorted

    const int cnt = atom_counts[b];

    if (tid < A_MAX) {
        sx[tid]  = X[(b * A_MAX + tid) * 3 + 0];
        sy[tid]  = X[(b * A_MAX + tid) * 3 + 1];
        sz[tid]  = X[(b * A_MAX + tid) * 3 + 2];
        sZa[tid] = Z[b * A_MAX + tid];
    }
    if (tid < NPAIRS) bcnt[tid] = 0;
    __syncthreads();

    const float xi = sx[i], yi = sy[i], zi = sz[i];
    const bool ivalid = (i < cnt);

    // ---- Phase A: ballot-compacted neighbor list + per-neighbor precompute ----
    if (tid < 64) {
        const int j = tid;
        bool flag = false;
        float dx = 0.f, dy = 0.f, dz = 0.f, r = 1.f;
        if (j < A_MAX) {
            dx = xi - sx[j]; dy = yi - sy[j]; dz = zi - sz[j];
            r = __builtin_amdgcn_sqrtf(dx * dx + dy * dy + dz * dz);
            flag = ivalid && (j < cnt) && (j != i) && (r < RCUT_F);
        }
        const unsigned long long mask = __ballot(flag ? 1 : 0);
        if (flag) {
            const int pos = __popcll(mask & ((1ull << tid) - 1ull));
            nb_dx[pos] = dx; nb_dy[pos] = dy; nb_dz[pos] = dz;
            nb_r[pos]  = r;  nb_r2[pos] = r * r;
            nb_rinv[pos] = __builtin_amdgcn_rcpf(r);
            nb_z[pos]  = sZa[j];
            const float fc = 0.5f * (__cosf(PI_F * r * (1.0f / RCUT_F)) + 1.0f);
            const float lr = __logf(r);
            const float s2 = log1pf(ETA2_F / (r * r));
            nb_fc[pos]   = fc;
            nb_mu[pos]   = lr - 0.5f * s2;
            nb_i2s2[pos] = 0.5f * __builtin_amdgcn_rcpf(s2);
            nb_pref[pos] = fc * __expf(-1.8f * lr) *
                           __builtin_amdgcn_rcpf(__builtin_amdgcn_sqrtf(s2) * SQRT_2PI_F);
        }
        if (tid == 0) nb_m = (int)__popcll(mask);
    }
    __syncthreads();
    const int m = nb_m;
    const int ntrip = m * (m - 1) / 2;

    float* orow = out + (size_t)bi * REPTOT;

    // ---- Phase B1: per-triplet pair-species index + within-bucket rank ----
    for (int t = tid; t < ntrip; t += 256) {
        int a, c;
        decode_tri(t, m, a, c);
        const int zj = nb_z[a], zk = nb_z[c];
        const int pmn = min(zj, zk), pmx = max(zj, zk);
        const int p = (pmn * (2 * NSPEC - pmn - 1)) / 2 + pmx;
        const int q = atomicAdd(&bcnt[p], 1);
        pq[t] = (unsigned short)(p | (q << 4));
    }
    __syncthreads();
    if (tid == 0) {
        int s = 0;
        for (int p = 0; p < NPAIRS; ++p) { bstart[p] = s; s += bcnt[p]; }
    }
    __syncthreads();

    // ---- Phase B2: geometry once per triplet, write directly to sorted slot ----
    for (int t = tid; t < ntrip; t += 256) {
        int a, c;
        decode_tri(t, m, a, c);

        const float rij = nb_r[a], rik = nb_r[c];
        const float r2ij = nb_r2[a], r2ik = nb_r2[c];
        const float rinv_a = nb_rinv[a], rinv_c = nb_rinv[c];
        const float djx = nb_dx[a], djy = nb_dy[a], djz = nb_dz[a];
        const float dkx = nb_dx[c], dky = nb_dy[c], dkz = nb_dz[c];

        float cosi = (djx * dkx + djy * dky + djz * dkz) * rinv_a * rinv_c;
        cosi = fminf(1.0f, fmaxf(-1.0f, cosi));

        // REFERENCE SEMANTICS: r_jk clamps to 1.0 when (j,k) pair not within cutoff
        const float ex = dkx - djx, ey = dky - djy, ez = dkz - djz;
        const float rjk2 = ex * ex + ey * ey + ez * ez;
        const float rjk = __builtin_amdgcn_sqrtf(rjk2);
        const bool w_jk = (rjk < RCUT_F);
        const float rjke  = w_jk ? rjk : 1.0f;
        const float rjke2 = w_jk ? rjk2 : 1.0f;
        const float rinv_jk = w_jk ? __builtin_amdgcn_rcpf(rjk) : 1.0f;

        const float cosj = (r2ij + rjke2 - r2ik) * 0.5f * rinv_a * rinv_jk;
        const float cosk = (r2ik + rjke2 - r2ij) * 0.5f * rinv_c * rinv_jk;

        const float ksi = W3_F * (1.0f + 3.0f * cosi * cosj * cosk)
                        * __expf(-0.57f * __logf(rij * rik * rjke));
        const float w  = ksi * nb_fc[a] * nb_fc[c];
        const float wc = w * cosi;
        const float s1 = fmaxf(1.0f - cosi * cosi, 0.0f);
        const float ws = w * __builtin_amdgcn_sqrtf(s1);
        const float d  = 0.5f * (rij + rik);

        const unsigned short e = pq[t];
        const int slot = bstart[e & 15] + (int)(e >> 4);
        trip[slot] = make_float4(wc, ws, d, 0.0f);
    }
    __syncthreads();

    // ---- Phase C (tid<200): (p,l) bucket reduction.  Tail (tid>=200): 2-body ----
    if (tid < NPAIRS * NRS3) {
        const int p = tid / NRS3;
        const int l = tid % NRS3;
        const float Rl = 0.3f * (float)(l + 1);   // RS3[l]
        const int s0 = bstart[p];
        const int s1 = s0 + bcnt[p];
        float ac = 0.0f, as_ = 0.0f;
        for (int s = s0; s < s1; ++s) {
            const float4 v = trip[s];              // ds_read_b128, 20-lane broadcast
            const float dd = v.z - Rl;
            const float rad = __expf(-ETA3_F * dd * dd);
            ac  += v.x * rad;
            as_ += v.y * rad;
        }
        orow[REP2 + p * (NRS3 * 2) + l * 2 + 0] = ac;
        orow[REP2 + p * (NRS3 * 2) + l * 2 + 1] = as_;
    } else {
        for (int t2 = tid - 200; t2 < REP2; t2 += 56) {
            const int s = t2 / NRS2;
            const int n = t2 % NRS2;
            const float Rn = 0.25f * (float)(n + 1);   // RS2[n]
            const float logRn = __logf(Rn);
            float acc = 0.0f;
            for (int a = 0; a < m; ++a) {
                if (nb_z[a] == s) {
                    const float dmu = logRn - nb_mu[a];
                    acc += nb_pref[a] * __expf(-dmu * dmu * nb_i2s2[a]);
                }
            }
            orow[t2] = acc * __builtin_amdgcn_rcpf(Rn);
        }
    }
}

extern "C" void kernel_launch(void* const* d_in, const int* in_sizes, int n_in,
                              void* d_out, int out_size, void* d_ws, size_t ws_size,
                              hipStream_t stream) {
    const float* X           = (const float*)d_in[0];
    const int*   Z           = (const int*)d_in[1];
    // d_in[2] = atomIDs, d_in[3] = molIDs (unused by reference math)
    const int*   atom_counts = (const int*)d_in[4];
    float* out = (float*)d_out;

    fchl_kernel<<<B_MOL * A_MAX, 256, 0, stream>>>(X, Z, atom_counts, out);
}

// Round 4
// 74.094 us; speedup vs baseline: 1.0263x; 1.0263x over previous
//
#include <hip/hip_runtime.h>
#include <math.h>

#define B_MOL 64
#define A_MAX 48
#define NSPEC 4
#define NRS2 24
#define NRS3 20
#define NPAIRS 10
#define REP2 (NSPEC * NRS2)        // 96
#define REP3 (NPAIRS * NRS3 * 2)   // 400
#define REPTOT (REP2 + REP3)       // 496
#define TRIP_CAP 1084              // >= 47*46/2 = 1081

#define RCUT_F 6.0f
#define ETA2_F 0.32f
#define ETA3_F 2.7f
#define PI_F 3.14159265358979323846f
#define W3_F 12.4225780586f        // sqrt(2.7/pi)*13.4
#define SQRT_2PI_F 2.5066282746310002f

// closed-form triplet decode: t -> (a, c), a < c < m, row-major over a
__device__ __forceinline__ void decode_tri(int t, int m, int& a_out, int& c_out) {
    const float fm = (float)(2 * m - 1);
    const float disc = fm * fm - 8.0f * (float)t;   // <= 8649, integer-exact in f32
    const float sq = __builtin_amdgcn_sqrtf(disc);
    int a = (int)((fm - sq) * 0.5f);
    if (a < 0) a = 0;
    while (a > 0 && (a * (2 * m - 1 - a)) / 2 > t) --a;
    while (((a + 1) * (2 * m - 1 - (a + 1))) / 2 <= t) ++a;
    a_out = a;
    c_out = t - (a * (2 * m - 1 - a)) / 2 + a + 1;
}

__global__ __launch_bounds__(256, 8) void fchl_kernel(
    const float* __restrict__ X, const int* __restrict__ Z,
    const int* __restrict__ atom_counts, float* __restrict__ out)
{
    const int bi = blockIdx.x;           // b*A_MAX + i
    const int b = bi / A_MAX;
    const int i = bi % A_MAX;
    const int tid = threadIdx.x;

    // compacted neighbor list (ballot compaction preserves order => a<c <=> j<k)
    __shared__ float nb_dx[A_MAX], nb_dy[A_MAX], nb_dz[A_MAX];
    __shared__ float nb_r[A_MAX], nb_r2[A_MAX], nb_rinv[A_MAX];
    __shared__ float nb_fc[A_MAX], nb_mu[A_MAX], nb_i2s2[A_MAX], nb_pref[A_MAX];
    __shared__ int   nb_z[A_MAX];
    __shared__ int   nb_m;
    __shared__ int   bcnt[NPAIRS], bstart[NPAIRS];
    __shared__ unsigned short pq[TRIP_CAP];                    // p | (rank<<4)
    __shared__ float trip_wc[TRIP_CAP], trip_ws[TRIP_CAP], trip_d[TRIP_CAP];
    // total LDS ~17.5 KB -> 8 blocks/CU (32-wave cap)

    const int cnt = atom_counts[b];
    float* orow = out + (size_t)bi * REPTOT;

    // whole-block early exit for invalid atoms (block-uniform condition)
    if (i >= cnt) {
        for (int t = tid; t < REPTOT; t += 256) orow[t] = 0.0f;
        return;
    }

    if (tid < NPAIRS) bcnt[tid] = 0;

    // i's coords: same address for all lanes -> one cacheline broadcast
    const float xi = X[(b * A_MAX + i) * 3 + 0];
    const float yi = X[(b * A_MAX + i) * 3 + 1];
    const float zi = X[(b * A_MAX + i) * 3 + 2];

    // ---- Phase A: ballot-compacted neighbor list + per-neighbor precompute ----
    if (tid < 64) {
        const int j = tid;
        bool flag = false;
        float dx = 0.f, dy = 0.f, dz = 0.f, r = 1.f;
        int zj = 0;
        if (j < A_MAX && j < cnt) {
            dx = xi - X[(b * A_MAX + j) * 3 + 0];
            dy = yi - X[(b * A_MAX + j) * 3 + 1];
            dz = zi - X[(b * A_MAX + j) * 3 + 2];
            zj = Z[b * A_MAX + j];
            r = __builtin_amdgcn_sqrtf(dx * dx + dy * dy + dz * dz);
            flag = (j != i) && (r < RCUT_F);
        }
        const unsigned long long mask = __ballot(flag ? 1 : 0);
        if (flag) {
            const int pos = __popcll(mask & ((1ull << tid) - 1ull));
            nb_dx[pos] = dx; nb_dy[pos] = dy; nb_dz[pos] = dz;
            nb_r[pos]  = r;  nb_r2[pos] = r * r;
            nb_rinv[pos] = __builtin_amdgcn_rcpf(r);
            nb_z[pos]  = zj;
            const float fc = 0.5f * (__cosf(PI_F * r * (1.0f / RCUT_F)) + 1.0f);
            const float lr = __logf(r);
            const float s2 = log1pf(ETA2_F / (r * r));
            nb_fc[pos]   = fc;
            nb_mu[pos]   = lr - 0.5f * s2;
            nb_i2s2[pos] = 0.5f * __builtin_amdgcn_rcpf(s2);
            nb_pref[pos] = fc * __expf(-1.8f * lr) *
                           __builtin_amdgcn_rcpf(__builtin_amdgcn_sqrtf(s2) * SQRT_2PI_F);
        }
        if (tid == 0) nb_m = (int)__popcll(mask);
    }
    __syncthreads();                                           // barrier 1
    const int m = nb_m;
    const int ntrip = m * (m - 1) / 2;

    // ---- Phase B1: per-triplet pair-species index + within-bucket rank ----
    for (int t = tid; t < ntrip; t += 256) {
        int a, c;
        decode_tri(t, m, a, c);
        const int zj = nb_z[a], zk = nb_z[c];
        const int pmn = min(zj, zk), pmx = max(zj, zk);
        const int p = (pmn * (2 * NSPEC - pmn - 1)) / 2 + pmx;
        const int q = atomicAdd(&bcnt[p], 1);
        pq[t] = (unsigned short)(p | (q << 4));
    }
    __syncthreads();                                           // barrier 2
    if (tid < NPAIRS) {       // parallel exclusive prefix (10 threads, <=9 adds)
        int s = 0;
        for (int p = 0; p < tid; ++p) s += bcnt[p];
        bstart[tid] = s;
    }
    __syncthreads();                                           // barrier 3

    // ---- Phase B2: geometry once per triplet, write directly to sorted slot ----
    for (int t = tid; t < ntrip; t += 256) {
        int a, c;
        decode_tri(t, m, a, c);

        const float rij = nb_r[a], rik = nb_r[c];
        const float r2ij = nb_r2[a], r2ik = nb_r2[c];
        const float rinv_a = nb_rinv[a], rinv_c = nb_rinv[c];
        const float djx = nb_dx[a], djy = nb_dy[a], djz = nb_dz[a];
        const float dkx = nb_dx[c], dky = nb_dy[c], dkz = nb_dz[c];

        float cosi = (djx * dkx + djy * dky + djz * dkz) * rinv_a * rinv_c;
        cosi = fminf(1.0f, fmaxf(-1.0f, cosi));

        // REFERENCE SEMANTICS: r_jk clamps to 1.0 when (j,k) pair not within cutoff
        const float ex = dkx - djx, ey = dky - djy, ez = dkz - djz;
        const float rjk2 = ex * ex + ey * ey + ez * ez;
        const float rjk = __builtin_amdgcn_sqrtf(rjk2);
        const bool w_jk = (rjk < RCUT_F);
        const float rjke  = w_jk ? rjk : 1.0f;
        const float rjke2 = w_jk ? rjk2 : 1.0f;
        const float rinv_jk = w_jk ? __builtin_amdgcn_rcpf(rjk) : 1.0f;

        const float cosj = (r2ij + rjke2 - r2ik) * 0.5f * rinv_a * rinv_jk;
        const float cosk = (r2ik + rjke2 - r2ij) * 0.5f * rinv_c * rinv_jk;

        const float ksi = W3_F * (1.0f + 3.0f * cosi * cosj * cosk)
                        * __expf(-0.57f * __logf(rij * rik * rjke));
        const float w  = ksi * nb_fc[a] * nb_fc[c];
        const float wc = w * cosi;
        const float s1 = fmaxf(1.0f - cosi * cosi, 0.0f);
        const float ws = w * __builtin_amdgcn_sqrtf(s1);
        const float d  = 0.5f * (rij + rik);

        const unsigned short e = pq[t];
        const int slot = bstart[e & 15] + (int)(e >> 4);
        trip_wc[slot] = wc; trip_ws[slot] = ws; trip_d[slot] = d;
    }
    __syncthreads();                                           // barrier 4

    // ---- Phase C (tid<200): (p,l) bucket reduction, software-pipelined.
    //      Tail (tid>=200): 2-body. ----
    if (tid < NPAIRS * NRS3) {
        const int p = tid / NRS3;
        const int l = tid % NRS3;
        const float Rl = 0.3f * (float)(l + 1);   // RS3[l]
        const int s0 = bstart[p];
        const int s1 = s0 + bcnt[p];
        float ac = 0.0f, as_ = 0.0f;
        if (s1 > s0) {
            float wcv = trip_wc[s0], wsv = trip_ws[s0], dv = trip_d[s0];
            for (int s = s0 + 1; s < s1; ++s) {
                const float wcn = trip_wc[s];      // prefetch s while computing s-1
                const float wsn = trip_ws[s];
                const float dn  = trip_d[s];
                const float dd = dv - Rl;
                const float rad = __expf(-ETA3_F * dd * dd);
                ac  += wcv * rad;
                as_ += wsv * rad;
                wcv = wcn; wsv = wsn; dv = dn;
            }
            const float dd = dv - Rl;
            const float rad = __expf(-ETA3_F * dd * dd);
            ac  += wcv * rad;
            as_ += wsv * rad;
        }
        orow[REP2 + p * (NRS3 * 2) + l * 2 + 0] = ac;
        orow[REP2 + p * (NRS3 * 2) + l * 2 + 1] = as_;
    } else {
        for (int t2 = tid - 200; t2 < REP2; t2 += 56) {
            const int s = t2 / NRS2;
            const int n = t2 % NRS2;
            const float Rn = 0.25f * (float)(n + 1);   // RS2[n]
            const float logRn = __logf(Rn);
            float acc = 0.0f;
            for (int a = 0; a < m; ++a) {
                if (nb_z[a] == s) {
                    const float dmu = logRn - nb_mu[a];
                    acc += nb_pref[a] * __expf(-dmu * dmu * nb_i2s2[a]);
                }
            }
            orow[t2] = acc * __builtin_amdgcn_rcpf(Rn);
        }
    }
}

extern "C" void kernel_launch(void* const* d_in, const int* in_sizes, int n_in,
                              void* d_out, int out_size, void* d_ws, size_t ws_size,
                              hipStream_t stream) {
    const float* X           = (const float*)d_in[0];
    const int*   Z           = (const int*)d_in[1];
    // d_in[2] = atomIDs, d_in[3] = molIDs (unused by reference math)
    const int*   atom_counts = (const int*)d_in[4];
    float* out = (float*)d_out;

    fchl_kernel<<<B_MOL * A_MAX, 256, 0, stream>>>(X, Z, atom_counts, out);
}